// Round 2
// baseline (485.594 us; speedup 1.0000x reference)
//
#include <hip/hip_runtime.h>
#include <hip/hip_bf16.h>

typedef __attribute__((ext_vector_type(8))) short bvec8;   // 8 x bf16
typedef __attribute__((ext_vector_type(4))) float fvec4;   // MFMA accumulator

__device__ __forceinline__ void splitf(float f, short& hi, short& lo) {
  __hip_bfloat16 h = __float2bfloat16(f);
  float r = f - __bfloat162float(h);
  __hip_bfloat16 l = __float2bfloat16(r);
  hi = *(short*)&h;
  lo = *(short*)&l;
}
__device__ __forceinline__ float bits2f(unsigned short u) {
  unsigned int v = ((unsigned int)u) << 16;
  return __uint_as_float(v);
}

// ---------------- CSR build ----------------
__global__ void k_degree(const int* __restrict__ ei, int* __restrict__ cnt, int E, int N) {
  int i = blockIdx.x * 256 + threadIdx.x;
  if (i >= E + N) return;
  int d = (i < E) ? ei[E + i] : (i - E);   // self loops appended
  atomicAdd(&cnt[d], 1);
}

// block-local scan: each block scans 4096 ints, writes local-prefixed off + block total
__global__ __launch_bounds__(1024) void k_scan_blk(const int* __restrict__ cnt, int* __restrict__ off,
                                                   int* __restrict__ bsum, int N) {
  __shared__ int wsum[16];
  int t = threadIdx.x, lane = t & 63, wv = t >> 6;
  int idx = blockIdx.x * 4096 + t * 4;
  int4 v = make_int4(0, 0, 0, 0);
  if (idx < N) v = *(const int4*)(cnt + idx);          // N % 4 == 0
  int s0 = v.x, s1 = s0 + v.y, s2 = s1 + v.z, s3 = s2 + v.w;
  int sc = s3;
  #pragma unroll
  for (int d = 1; d < 64; d <<= 1) {
    int u = __shfl_up(sc, d, 64);
    if (lane >= d) sc += u;
  }
  if (lane == 63) wsum[wv] = sc;
  __syncthreads();
  int woff = 0;
  #pragma unroll
  for (int w = 0; w < 16; ++w) woff += (w < wv) ? wsum[w] : 0;
  int eb = woff + sc - s3;                             // local exclusive prefix
  if (idx < N) {
    int4 o = make_int4(eb, eb + s0, eb + s1, eb + s2);
    *(int4*)(off + idx) = o;
  }
  if (t == 1023) bsum[blockIdx.x] = woff + sc;         // block total
}

__global__ void k_scan_top(int* __restrict__ bsum, int* __restrict__ off, int nb, int N) {
  if (threadIdx.x == 0) {
    int ex = 0;
    for (int i = 0; i < nb; ++i) { int tv = bsum[i]; bsum[i] = ex; ex += tv; }
    off[N] = ex;
  }
}

__global__ __launch_bounds__(1024) void k_scan_add(int* __restrict__ off, int* __restrict__ cur,
                                                   const int* __restrict__ bsum, int N) {
  int t = threadIdx.x;
  int idx = blockIdx.x * 4096 + t * 4;
  if (idx >= N) return;
  int b = bsum[blockIdx.x];
  int4 o = *(const int4*)(off + idx);
  o.x += b; o.y += b; o.z += b; o.w += b;
  *(int4*)(off + idx) = o;
  *(int4*)(cur + idx) = o;
}

__global__ void k_scatter(const int* __restrict__ ei, int* __restrict__ cur, int* __restrict__ csr, int E, int N) {
  int i = blockIdx.x * 256 + threadIdx.x;
  if (i >= E + N) return;
  int s, d;
  if (i < E) { s = ei[i]; d = ei[E + i]; } else { s = i - E; d = i - E; }
  int p = atomicAdd(&cur[d], 1);
  csr[p] = s;
}

// ---------------- pack Wg0/Wg1/Wt into MFMA-fragment order (hi/lo bf16 planes) ----------------
// blocks 0..31: Wg0 ; 32..63: Wg1 ; 64..127: Wt
__global__ __launch_bounds__(64) void k_prep(const float* __restrict__ Wg0, const float* __restrict__ Wg1,
                                             const float* __restrict__ Wt,
                                             short* __restrict__ pk0, short* __restrict__ pk1,
                                             short* __restrict__ wtpk) {
  int b = blockIdx.x;
  int lane = threadIdx.x;
  int fq = lane >> 4, fr = lane & 15;
  bvec8 hv, lv;
  if (b < 64) {
    const float* Wg = (b < 32) ? Wg0 : Wg1;
    short* pk = (b < 32) ? pk0 : pk1;
    int tile = b & 31;
    int w = tile >> 3, s = (tile >> 2) & 1, ct = tile & 3;
    #pragma unroll
    for (int j = 0; j < 8; ++j) {
      short hh, ll;
      splitf(Wg[(size_t)(s * 32 + fq * 8 + j) * 256 + w * 64 + ct * 16 + fr], hh, ll);
      hv[j] = hh; lv[j] = ll;
    }
    *(bvec8*)(pk + tile * 1024 + lane * 8) = hv;
    *(bvec8*)(pk + tile * 1024 + 512 + lane * 8) = lv;
  } else {
    int tile = b - 64;            // 0..63
    int s = tile >> 2, nt = tile & 3;
    #pragma unroll
    for (int j = 0; j < 8; ++j) {
      short hh, ll;
      splitf(Wt[(size_t)(s * 32 + fq * 8 + j) * 64 + nt * 16 + fr], hh, ll);
      hv[j] = hh; lv[j] = ll;
    }
    *(bvec8*)(wtpk + tile * 1024 + lane * 8) = hv;
    *(bvec8*)(wtpk + tile * 1024 + 512 + lane * 8) = lv;
  }
}

// ---------------- x0 = feat @ Wt + bt  (split-bf16 MFMA, no LDS, no barriers) ----------------
// block = 256 thr (4 waves), each wave owns 32 rows (M=2 row-tiles); block covers 128 rows.
__global__ __launch_bounds__(256) void k_x0(const float* __restrict__ feat, const short* __restrict__ wtpk,
                                            const float* __restrict__ bt,
                                            short* __restrict__ xhi, short* __restrict__ xlo, int N) {
  const int t = threadIdx.x;
  const int lane = t & 63;
  const int w = t >> 6;
  const int fr = lane & 15;
  const int fq = lane >> 4;
  const int n0 = blockIdx.x * 128;

  int ar0 = n0 + w * 32 + fr;      if (ar0 >= N) ar0 = N - 1;
  int ar1 = n0 + w * 32 + 16 + fr; if (ar1 >= N) ar1 = N - 1;
  const float* fb0 = feat + (size_t)ar0 * 512 + fq * 8;
  const float* fb1 = feat + (size_t)ar1 * 512 + fq * 8;

  fvec4 acc[2][4];
  #pragma unroll
  for (int m = 0; m < 2; ++m)
    #pragma unroll
    for (int nt = 0; nt < 4; ++nt) acc[m][nt] = (fvec4){0.f, 0.f, 0.f, 0.f};

  for (int s = 0; s < 16; ++s) {
    bvec8 bh[4], bl[4];
    #pragma unroll
    for (int nt = 0; nt < 4; ++nt) {
      bh[nt] = *(const bvec8*)(wtpk + (s * 4 + nt) * 1024 + lane * 8);
      bl[nt] = *(const bvec8*)(wtpk + (s * 4 + nt) * 1024 + 512 + lane * 8);
    }
    #pragma unroll
    for (int m = 0; m < 2; ++m) {
      const float* fb = m ? fb1 : fb0;
      float4 f0 = *(const float4*)(fb + s * 32);
      float4 f1 = *(const float4*)(fb + s * 32 + 4);
      float fv[8] = {f0.x, f0.y, f0.z, f0.w, f1.x, f1.y, f1.z, f1.w};
      bvec8 ah, al;
      #pragma unroll
      for (int j = 0; j < 8; ++j) { short hh, ll; splitf(fv[j], hh, ll); ah[j] = hh; al[j] = ll; }
      #pragma unroll
      for (int nt = 0; nt < 4; ++nt) {
        acc[m][nt] = __builtin_amdgcn_mfma_f32_16x16x32_bf16(ah, bh[nt], acc[m][nt], 0, 0, 0);
        acc[m][nt] = __builtin_amdgcn_mfma_f32_16x16x32_bf16(ah, bl[nt], acc[m][nt], 0, 0, 0);
        acc[m][nt] = __builtin_amdgcn_mfma_f32_16x16x32_bf16(al, bh[nt], acc[m][nt], 0, 0, 0);
      }
    }
  }
  #pragma unroll
  for (int m = 0; m < 2; ++m)
    #pragma unroll
    for (int nt = 0; nt < 4; ++nt) {
      float btv = bt[nt * 16 + fr];
      #pragma unroll
      for (int r = 0; r < 4; ++r) {
        int node = n0 + w * 32 + m * 16 + fq * 4 + r;
        if (node < N) {
          short hh, ll;
          splitf(acc[m][nt][r] + btv, hh, ll);
          xhi[(size_t)node * 64 + nt * 16 + fr] = hh;
          xlo[(size_t)node * 64 + nt * 16 + fr] = ll;
        }
      }
    }
}

// ---------------- h = x @ Wg (split-bf16 MFMA, pre-packed both sides, no LDS) ; al_s/al_d ----------------
__global__ __launch_bounds__(256) void k_h(const short* __restrict__ xhi, const short* __restrict__ xlo,
                                           const short* __restrict__ pk,
                                           const float* __restrict__ as_, const float* __restrict__ ad_,
                                           __hip_bfloat16* __restrict__ h, float* __restrict__ als,
                                           float* __restrict__ ald, int N) {
  const int t = threadIdx.x;
  const int lane = t & 63;
  const int w = t >> 6;          // wave == head
  const int fr = lane & 15;
  const int fq = lane >> 4;
  const int n0 = blockIdx.x * 64;

  bvec8 bh[2][4], bl[2][4];
  #pragma unroll
  for (int s = 0; s < 2; ++s)
    #pragma unroll
    for (int ct = 0; ct < 4; ++ct) {
      int tile = (w * 2 + s) * 4 + ct;
      bh[s][ct] = *(const bvec8*)(pk + tile * 1024 + lane * 8);
      bl[s][ct] = *(const bvec8*)(pk + tile * 1024 + 512 + lane * 8);
    }
  fvec4 acc[4][4];   // [nt][ct]
  #pragma unroll
  for (int nt = 0; nt < 4; ++nt)
    #pragma unroll
    for (int ct = 0; ct < 4; ++ct) acc[nt][ct] = (fvec4){0.f, 0.f, 0.f, 0.f};
  #pragma unroll
  for (int nt = 0; nt < 4; ++nt) {
    int row = n0 + nt * 16 + fr; if (row >= N) row = N - 1;
    const short* xh = xhi + (size_t)row * 64 + fq * 8;
    const short* xl = xlo + (size_t)row * 64 + fq * 8;
    #pragma unroll
    for (int s = 0; s < 2; ++s) {
      const bvec8 ah = *(const bvec8*)(xh + s * 32);
      const bvec8 al = *(const bvec8*)(xl + s * 32);
      #pragma unroll
      for (int ct = 0; ct < 4; ++ct) {
        acc[nt][ct] = __builtin_amdgcn_mfma_f32_16x16x32_bf16(ah, bh[s][ct], acc[nt][ct], 0, 0, 0);
        acc[nt][ct] = __builtin_amdgcn_mfma_f32_16x16x32_bf16(ah, bl[s][ct], acc[nt][ct], 0, 0, 0);
        acc[nt][ct] = __builtin_amdgcn_mfma_f32_16x16x32_bf16(al, bh[s][ct], acc[nt][ct], 0, 0, 0);
      }
    }
  }
  float asv[4], adv[4];
  #pragma unroll
  for (int ct = 0; ct < 4; ++ct) {
    asv[ct] = as_[w * 64 + ct * 16 + fr];
    adv[ct] = ad_[w * 64 + ct * 16 + fr];
  }
  #pragma unroll
  for (int nt = 0; nt < 4; ++nt) {
    #pragma unroll
    for (int r = 0; r < 4; ++r) {
      int n = n0 + nt * 16 + fq * 4 + r;
      float ps = 0.f, pd = 0.f;
      #pragma unroll
      for (int ct = 0; ct < 4; ++ct) {
        ps = fmaf(acc[nt][ct][r], asv[ct], ps);
        pd = fmaf(acc[nt][ct][r], adv[ct], pd);
      }
      #pragma unroll
      for (int m = 1; m < 16; m <<= 1) { ps += __shfl_xor(ps, m, 64); pd += __shfl_xor(pd, m, 64); }
      if (fr == 0 && n < N) { als[(size_t)n * 4 + w] = ps; ald[(size_t)n * 4 + w] = pd; }
      #pragma unroll
      for (int ct = 0; ct < 4; ++ct)
        if (n < N) h[(size_t)n * 256 + w * 64 + ct * 16 + fr] = __float2bfloat16(acc[nt][ct][r]);
    }
  }
}

// ---------------- attention aggregate (4-wide loop) + epilogue [+ fused final] ----------------
template <bool FINAL>
__global__ __launch_bounds__(256) void k_agg(const __hip_bfloat16* __restrict__ h, const float* __restrict__ als,
                                             const float* __restrict__ ald, const int* __restrict__ off,
                                             const int* __restrict__ csr, const float* __restrict__ bg,
                                             const float* __restrict__ gam, const float* __restrict__ bet,
                                             const float* __restrict__ pa,
                                             short* __restrict__ xhi, short* __restrict__ xlo,
                                             const float* __restrict__ Wp, const float* __restrict__ bp,
                                             float* __restrict__ out, int N) {
  int lane = threadIdx.x & 63;
  int n = blockIdx.x * 4 + (threadIdx.x >> 6);
  if (n >= N) return;
  int hh = lane >> 4;
  int cg = (lane & 15) * 4;
  float aldv = ald[(size_t)n * 4 + hh];
  int e0 = __builtin_amdgcn_readfirstlane(off[n]);
  int e1 = __builtin_amdgcn_readfirstlane(off[n + 1]);
  float a0 = 0, a1 = 0, a2 = 0, a3 = 0, den = 0;
  const unsigned short* hb = (const unsigned short*)h;
  const int co = hh * 64 + cg;
  int e = e0;
  for (; e + 4 <= e1; e += 4) {
    int s0 = csr[e + 0], s1 = csr[e + 1], s2 = csr[e + 2], s3 = csr[e + 3];
    float q0 = als[(size_t)s0 * 4 + hh];
    float q1 = als[(size_t)s1 * 4 + hh];
    float q2 = als[(size_t)s2 * 4 + hh];
    float q3 = als[(size_t)s3 * 4 + hh];
    ushort4 g0 = *(const ushort4*)(hb + (size_t)s0 * 256 + co);
    ushort4 g1 = *(const ushort4*)(hb + (size_t)s1 * 256 + co);
    ushort4 g2 = *(const ushort4*)(hb + (size_t)s2 * 256 + co);
    ushort4 g3 = *(const ushort4*)(hb + (size_t)s3 * 256 + co);
    float t0 = q0 + aldv; t0 = fmaxf(t0, 0.2f * t0); float w0 = __expf(t0);
    float t1 = q1 + aldv; t1 = fmaxf(t1, 0.2f * t1); float w1 = __expf(t1);
    float t2 = q2 + aldv; t2 = fmaxf(t2, 0.2f * t2); float w2 = __expf(t2);
    float t3 = q3 + aldv; t3 = fmaxf(t3, 0.2f * t3); float w3 = __expf(t3);
    den += (w0 + w1) + (w2 + w3);
    a0 += w0 * bits2f(g0.x) + w1 * bits2f(g1.x) + w2 * bits2f(g2.x) + w3 * bits2f(g3.x);
    a1 += w0 * bits2f(g0.y) + w1 * bits2f(g1.y) + w2 * bits2f(g2.y) + w3 * bits2f(g3.y);
    a2 += w0 * bits2f(g0.z) + w1 * bits2f(g1.z) + w2 * bits2f(g2.z) + w3 * bits2f(g3.z);
    a3 += w0 * bits2f(g0.w) + w1 * bits2f(g1.w) + w2 * bits2f(g2.w) + w3 * bits2f(g3.w);
  }
  for (; e < e1; ++e) {
    int s = csr[e];
    float t = als[(size_t)s * 4 + hh] + aldv;
    t = fmaxf(t, 0.2f * t);
    float w = __expf(t);
    den += w;
    const ushort4 hv = *(const ushort4*)(hb + (size_t)s * 256 + co);
    a0 += w * bits2f(hv.x); a1 += w * bits2f(hv.y); a2 += w * bits2f(hv.z); a3 += w * bits2f(hv.w);
  }
  float inv = 1.0f / den;
  a0 *= inv; a1 *= inv; a2 *= inv; a3 *= inv;
  a0 += __shfl_xor(a0, 16, 64); a0 += __shfl_xor(a0, 32, 64);
  a1 += __shfl_xor(a1, 16, 64); a1 += __shfl_xor(a1, 32, 64);
  a2 += __shfl_xor(a2, 16, 64); a2 += __shfl_xor(a2, 32, 64);
  a3 += __shfl_xor(a3, 16, 64); a3 += __shfl_xor(a3, 32, 64);
  float v0 = a0 * 0.25f + bg[cg + 0];
  float v1 = a1 * 0.25f + bg[cg + 1];
  float v2 = a2 * 0.25f + bg[cg + 2];
  float v3 = a3 * 0.25f + bg[cg + 3];
  float sum = v0 + v1 + v2 + v3;
  #pragma unroll
  for (int m = 1; m < 16; m <<= 1) sum += __shfl_xor(sum, m, 64);
  float mu = sum * (1.f / 64.f);
  float d0 = v0 - mu, d1 = v1 - mu, d2 = v2 - mu, d3 = v3 - mu;
  float vv = d0 * d0 + d1 * d1 + d2 * d2 + d3 * d3;
  #pragma unroll
  for (int m = 1; m < 16; m <<= 1) vv += __shfl_xor(vv, m, 64);
  float rstd = rsqrtf(vv * (1.f / 64.f) + 1e-5f);
  float A = pa[0];
  float y0 = d0 * rstd * gam[cg + 0] + bet[cg + 0];
  float y1 = d1 * rstd * gam[cg + 1] + bet[cg + 1];
  float y2 = d2 * rstd * gam[cg + 2] + bet[cg + 2];
  float y3 = d3 * rstd * gam[cg + 3] + bet[cg + 3];
  y0 = y0 > 0.f ? y0 : A * y0;
  y1 = y1 > 0.f ? y1 : A * y1;
  y2 = y2 > 0.f ? y2 : A * y2;
  y3 = y3 > 0.f ? y3 : A * y3;
  // residual row (valid in lanes 0..15, 4 ch each) from split planes
  float o0 = 0.f, o1 = 0.f, o2 = 0.f, o3 = 0.f;
  if (lane < 16) {
    ushort4 xh = *(const ushort4*)((const unsigned short*)xhi + (size_t)n * 64 + cg);
    ushort4 xl = *(const ushort4*)((const unsigned short*)xlo + (size_t)n * 64 + cg);
    o0 = bits2f(xh.x) + bits2f(xl.x) + y0;
    o1 = bits2f(xh.y) + bits2f(xl.y) + y1;
    o2 = bits2f(xh.z) + bits2f(xl.z) + y2;
    o3 = bits2f(xh.w) + bits2f(xl.w) + y3;
  }
  if (!FINAL) {
    if (lane < 16) {
      short h0, l0, h1, l1, h2, l2, h3, l3;
      splitf(o0, h0, l0); splitf(o1, h1, l1); splitf(o2, h2, l2); splitf(o3, h3, l3);
      ushort4 oh = make_ushort4((unsigned short)h0, (unsigned short)h1, (unsigned short)h2, (unsigned short)h3);
      ushort4 ol = make_ushort4((unsigned short)l0, (unsigned short)l1, (unsigned short)l2, (unsigned short)l3);
      *(ushort4*)((unsigned short*)xhi + (size_t)n * 64 + cg) = oh;   // in place: only this wave touches row n
      *(ushort4*)((unsigned short*)xlo + (size_t)n * 64 + cg) = ol;
    }
  } else {
    // z = row @ Wp + bp ; L2-normalize ; out
    float acc = bp[lane];
    #pragma unroll
    for (int g = 0; g < 16; ++g) {
      float rx = __shfl(o0, g, 64), ry = __shfl(o1, g, 64);
      float rz = __shfl(o2, g, 64), rw = __shfl(o3, g, 64);
      const float* wp = Wp + g * 4 * 64 + lane;
      acc = fmaf(rx, wp[0],   acc);
      acc = fmaf(ry, wp[64],  acc);
      acc = fmaf(rz, wp[128], acc);
      acc = fmaf(rw, wp[192], acc);
    }
    float sq = acc * acc;
    #pragma unroll
    for (int m = 1; m < 64; m <<= 1) sq += __shfl_xor(sq, m, 64);
    float nrm = fmaxf(sqrtf(sq), 1e-12f);
    out[(size_t)n * 64 + lane] = acc / nrm;
  }
}

extern "C" void kernel_launch(void* const* d_in, const int* in_sizes, int n_in,
                              void* d_out, int out_size, void* d_ws, size_t ws_size,
                              hipStream_t stream) {
  const float* feat = (const float*)d_in[0];
  const int*   ei   = (const int*)d_in[1];
  const float* Wt   = (const float*)d_in[2];
  const float* bt   = (const float*)d_in[3];
  const float* Wp   = (const float*)d_in[4];
  const float* bp   = (const float*)d_in[5];
  const float* Wg[2]  = {(const float*)d_in[6],  (const float*)d_in[13]};
  const float* as_[2] = {(const float*)d_in[7],  (const float*)d_in[14]};
  const float* ad_[2] = {(const float*)d_in[8],  (const float*)d_in[15]};
  const float* bg[2]  = {(const float*)d_in[9],  (const float*)d_in[16]};
  const float* gm[2]  = {(const float*)d_in[10], (const float*)d_in[17]};
  const float* be[2]  = {(const float*)d_in[11], (const float*)d_in[18]};
  const float* pa[2]  = {(const float*)d_in[12], (const float*)d_in[19]};

  const int N = in_sizes[0] / 512;
  const int E = in_sizes[1] / 2;

  // workspace layout
  short* xhi = (short*)d_ws;                                  // N*64 bf16-hi plane
  short* xlo = xhi + (size_t)N * 64;                          // N*64 bf16-lo plane
  __hip_bfloat16* hb = (__hip_bfloat16*)(xlo + (size_t)N * 64); // N*256 bf16
  float* als = (float*)((short*)hb + (size_t)N * 256);        // N*4
  float* ald = als + (size_t)N * 4;                           // N*4
  int* cnt = (int*)(ald + (size_t)N * 4);                     // N
  int* cur = cnt + N;                                         // N
  int* csr = cur + N;                                         // E+N
  int* off = csr + (E + N);                                   // N+1
  int* bsum = off + (N + 1);                                  // 16
  short* pk0 = (short*)(((uintptr_t)(bsum + 16) + 15) & ~(uintptr_t)15);  // 32768 shorts
  short* pk1 = pk0 + 32768;
  short* wtpk = pk1 + 32768;                                  // 65536 shorts

  hipMemsetAsync(cnt, 0, (size_t)N * sizeof(int), stream);
  int eb = (E + N + 255) / 256;
  int SB = (N + 4095) / 4096;
  k_degree<<<eb, 256, 0, stream>>>(ei, cnt, E, N);
  k_prep<<<128, 64, 0, stream>>>(Wg[0], Wg[1], Wt, pk0, pk1, wtpk);
  k_scan_blk<<<SB, 1024, 0, stream>>>(cnt, off, bsum, N);
  k_scan_top<<<1, 64, 0, stream>>>(bsum, off, SB, N);
  k_scan_add<<<SB, 1024, 0, stream>>>(off, cur, bsum, N);
  k_scatter<<<eb, 256, 0, stream>>>(ei, cur, csr, E, N);

  int nb4 = (N + 3) / 4;
  int nb64 = (N + 63) / 64;
  int nb128 = (N + 127) / 128;
  k_x0<<<nb128, 256, 0, stream>>>(feat, wtpk, bt, xhi, xlo, N);

  k_h<<<nb64, 256, 0, stream>>>(xhi, xlo, pk0, as_[0], ad_[0], hb, als, ald, N);
  k_agg<false><<<nb4, 256, 0, stream>>>(hb, als, ald, off, csr, bg[0], gm[0], be[0], pa[0],
                                        xhi, xlo, Wp, bp, (float*)d_out, N);
  k_h<<<nb64, 256, 0, stream>>>(xhi, xlo, pk1, as_[1], ad_[1], hb, als, ald, N);
  k_agg<true><<<nb4, 256, 0, stream>>>(hb, als, ald, off, csr, bg[1], gm[1], be[1], pa[1],
                                       xhi, xlo, Wp, bp, (float*)d_out, N);
}

// Round 3
// 474.982 us; speedup vs baseline: 1.0223x; 1.0223x over previous
//
#include <hip/hip_runtime.h>
#include <hip/hip_bf16.h>

typedef __attribute__((ext_vector_type(8))) short bvec8;   // 8 x bf16
typedef __attribute__((ext_vector_type(4))) float fvec4;   // MFMA accumulator

__device__ __forceinline__ void splitf(float f, short& hi, short& lo) {
  __hip_bfloat16 h = __float2bfloat16(f);
  float r = f - __bfloat162float(h);
  __hip_bfloat16 l = __float2bfloat16(r);
  hi = *(short*)&h;
  lo = *(short*)&l;
}
__device__ __forceinline__ float bits2f(unsigned short u) {
  unsigned int v = ((unsigned int)u) << 16;
  return __uint_as_float(v);
}

// ---------------- CSR build ----------------
__global__ void k_degree(const int* __restrict__ ei, int* __restrict__ cnt, int E, int N) {
  int i = blockIdx.x * 256 + threadIdx.x;
  if (i >= E + N) return;
  int d = (i < E) ? ei[E + i] : (i - E);   // self loops appended
  atomicAdd(&cnt[d], 1);
}

// block-local scan: each block scans 4096 ints, writes local-prefixed off + block total
__global__ __launch_bounds__(1024) void k_scan_blk(const int* __restrict__ cnt, int* __restrict__ off,
                                                   int* __restrict__ bsum, int N) {
  __shared__ int wsum[16];
  int t = threadIdx.x, lane = t & 63, wv = t >> 6;
  int idx = blockIdx.x * 4096 + t * 4;
  int4 v = make_int4(0, 0, 0, 0);
  if (idx < N) v = *(const int4*)(cnt + idx);          // N % 4 == 0
  int s0 = v.x, s1 = s0 + v.y, s2 = s1 + v.z, s3 = s2 + v.w;
  int sc = s3;
  #pragma unroll
  for (int d = 1; d < 64; d <<= 1) {
    int u = __shfl_up(sc, d, 64);
    if (lane >= d) sc += u;
  }
  if (lane == 63) wsum[wv] = sc;
  __syncthreads();
  int woff = 0;
  #pragma unroll
  for (int w = 0; w < 16; ++w) woff += (w < wv) ? wsum[w] : 0;
  int eb = woff + sc - s3;                             // local exclusive prefix
  if (idx < N) {
    int4 o = make_int4(eb, eb + s0, eb + s1, eb + s2);
    *(int4*)(off + idx) = o;
  }
  if (t == 1023) bsum[blockIdx.x] = woff + sc;         // block total
}

// add block-prefix (computed inline from bsum, <=13 blocks) ; off[N] = total analytically
__global__ __launch_bounds__(1024) void k_scan_add(int* __restrict__ off, int* __restrict__ cur,
                                                   const int* __restrict__ bsum, int total, int N) {
  int t = threadIdx.x;
  if (blockIdx.x == 0 && t == 0) off[N] = total;
  int b = 0;
  for (int i = 0; i < blockIdx.x; ++i) b += bsum[i];
  int idx = blockIdx.x * 4096 + t * 4;
  if (idx >= N) return;
  int4 o = *(const int4*)(off + idx);
  o.x += b; o.y += b; o.z += b; o.w += b;
  *(int4*)(off + idx) = o;
  *(int4*)(cur + idx) = o;
}

__global__ void k_scatter(const int* __restrict__ ei, int* __restrict__ cur, int* __restrict__ csr, int E, int N) {
  int i = blockIdx.x * 256 + threadIdx.x;
  if (i >= E + N) return;
  int s, d;
  if (i < E) { s = ei[i]; d = ei[E + i]; } else { s = i - E; d = i - E; }
  int p = atomicAdd(&cur[d], 1);
  csr[p] = s;
}

// ---------------- pack Wg0/Wg1/Wt into MFMA-fragment order (hi/lo bf16 planes) ----------------
// blocks 0..31: Wg0 ; 32..63: Wg1 ; 64..127: Wt
__global__ __launch_bounds__(64) void k_prep(const float* __restrict__ Wg0, const float* __restrict__ Wg1,
                                             const float* __restrict__ Wt,
                                             short* __restrict__ pk0, short* __restrict__ pk1,
                                             short* __restrict__ wtpk) {
  int b = blockIdx.x;
  int lane = threadIdx.x;
  int fq = lane >> 4, fr = lane & 15;
  bvec8 hv, lv;
  if (b < 64) {
    const float* Wg = (b < 32) ? Wg0 : Wg1;
    short* pk = (b < 32) ? pk0 : pk1;
    int tile = b & 31;
    int w = tile >> 3, s = (tile >> 2) & 1, ct = tile & 3;
    #pragma unroll
    for (int j = 0; j < 8; ++j) {
      short hh, ll;
      splitf(Wg[(size_t)(s * 32 + fq * 8 + j) * 256 + w * 64 + ct * 16 + fr], hh, ll);
      hv[j] = hh; lv[j] = ll;
    }
    *(bvec8*)(pk + tile * 1024 + lane * 8) = hv;
    *(bvec8*)(pk + tile * 1024 + 512 + lane * 8) = lv;
  } else {
    int tile = b - 64;            // 0..63
    int s = tile >> 2, nt = tile & 3;
    #pragma unroll
    for (int j = 0; j < 8; ++j) {
      short hh, ll;
      splitf(Wt[(size_t)(s * 32 + fq * 8 + j) * 64 + nt * 16 + fr], hh, ll);
      hv[j] = hh; lv[j] = ll;
    }
    *(bvec8*)(wtpk + tile * 1024 + lane * 8) = hv;
    *(bvec8*)(wtpk + tile * 1024 + 512 + lane * 8) = lv;
  }
}

// ---------------- x0 = feat @ Wt + bt  (split-bf16 MFMA, no LDS, no barriers) ----------------
__global__ __launch_bounds__(256) void k_x0(const float* __restrict__ feat, const short* __restrict__ wtpk,
                                            const float* __restrict__ bt,
                                            short* __restrict__ xhi, short* __restrict__ xlo, int N) {
  const int t = threadIdx.x;
  const int lane = t & 63;
  const int w = t >> 6;
  const int fr = lane & 15;
  const int fq = lane >> 4;
  const int n0 = blockIdx.x * 128;

  int ar0 = n0 + w * 32 + fr;      if (ar0 >= N) ar0 = N - 1;
  int ar1 = n0 + w * 32 + 16 + fr; if (ar1 >= N) ar1 = N - 1;
  const float* fb0 = feat + (size_t)ar0 * 512 + fq * 8;
  const float* fb1 = feat + (size_t)ar1 * 512 + fq * 8;

  fvec4 acc[2][4];
  #pragma unroll
  for (int m = 0; m < 2; ++m)
    #pragma unroll
    for (int nt = 0; nt < 4; ++nt) acc[m][nt] = (fvec4){0.f, 0.f, 0.f, 0.f};

  for (int s = 0; s < 16; ++s) {
    bvec8 bh[4], bl[4];
    #pragma unroll
    for (int nt = 0; nt < 4; ++nt) {
      bh[nt] = *(const bvec8*)(wtpk + (s * 4 + nt) * 1024 + lane * 8);
      bl[nt] = *(const bvec8*)(wtpk + (s * 4 + nt) * 1024 + 512 + lane * 8);
    }
    #pragma unroll
    for (int m = 0; m < 2; ++m) {
      const float* fb = m ? fb1 : fb0;
      float4 f0 = *(const float4*)(fb + s * 32);
      float4 f1 = *(const float4*)(fb + s * 32 + 4);
      float fv[8] = {f0.x, f0.y, f0.z, f0.w, f1.x, f1.y, f1.z, f1.w};
      bvec8 ah, al;
      #pragma unroll
      for (int j = 0; j < 8; ++j) { short hh, ll; splitf(fv[j], hh, ll); ah[j] = hh; al[j] = ll; }
      #pragma unroll
      for (int nt = 0; nt < 4; ++nt) {
        acc[m][nt] = __builtin_amdgcn_mfma_f32_16x16x32_bf16(ah, bh[nt], acc[m][nt], 0, 0, 0);
        acc[m][nt] = __builtin_amdgcn_mfma_f32_16x16x32_bf16(ah, bl[nt], acc[m][nt], 0, 0, 0);
        acc[m][nt] = __builtin_amdgcn_mfma_f32_16x16x32_bf16(al, bh[nt], acc[m][nt], 0, 0, 0);
      }
    }
  }
  #pragma unroll
  for (int m = 0; m < 2; ++m)
    #pragma unroll
    for (int nt = 0; nt < 4; ++nt) {
      float btv = bt[nt * 16 + fr];
      #pragma unroll
      for (int r = 0; r < 4; ++r) {
        int node = n0 + w * 32 + m * 16 + fq * 4 + r;
        if (node < N) {
          short hh, ll;
          splitf(acc[m][nt][r] + btv, hh, ll);
          xhi[(size_t)node * 64 + nt * 16 + fr] = hh;
          xlo[(size_t)node * 64 + nt * 16 + fr] = ll;
        }
      }
    }
}

// ---------------- h = x @ Wg ; h quantized int8 (per-row-head absmax scale) ; al_s/al_d ----------------
// alsc layout: [N][4] float2 {als, scale} ; ald: [N][4] float
__global__ __launch_bounds__(256) void k_h(const short* __restrict__ xhi, const short* __restrict__ xlo,
                                           const short* __restrict__ pk,
                                           const float* __restrict__ as_, const float* __restrict__ ad_,
                                           signed char* __restrict__ h8, float2* __restrict__ alsc,
                                           float* __restrict__ ald, int N) {
  const int t = threadIdx.x;
  const int lane = t & 63;
  const int w = t >> 6;          // wave == head
  const int fr = lane & 15;
  const int fq = lane >> 4;
  const int n0 = blockIdx.x * 64;

  bvec8 bh[2][4], bl[2][4];
  #pragma unroll
  for (int s = 0; s < 2; ++s)
    #pragma unroll
    for (int ct = 0; ct < 4; ++ct) {
      int tile = (w * 2 + s) * 4 + ct;
      bh[s][ct] = *(const bvec8*)(pk + tile * 1024 + lane * 8);
      bl[s][ct] = *(const bvec8*)(pk + tile * 1024 + 512 + lane * 8);
    }
  fvec4 acc[4][4];   // [nt][ct]
  #pragma unroll
  for (int nt = 0; nt < 4; ++nt)
    #pragma unroll
    for (int ct = 0; ct < 4; ++ct) acc[nt][ct] = (fvec4){0.f, 0.f, 0.f, 0.f};
  #pragma unroll
  for (int nt = 0; nt < 4; ++nt) {
    int row = n0 + nt * 16 + fr; if (row >= N) row = N - 1;
    const short* xh = xhi + (size_t)row * 64 + fq * 8;
    const short* xl = xlo + (size_t)row * 64 + fq * 8;
    #pragma unroll
    for (int s = 0; s < 2; ++s) {
      const bvec8 ah = *(const bvec8*)(xh + s * 32);
      const bvec8 al = *(const bvec8*)(xl + s * 32);
      #pragma unroll
      for (int ct = 0; ct < 4; ++ct) {
        acc[nt][ct] = __builtin_amdgcn_mfma_f32_16x16x32_bf16(ah, bh[s][ct], acc[nt][ct], 0, 0, 0);
        acc[nt][ct] = __builtin_amdgcn_mfma_f32_16x16x32_bf16(ah, bl[s][ct], acc[nt][ct], 0, 0, 0);
        acc[nt][ct] = __builtin_amdgcn_mfma_f32_16x16x32_bf16(al, bh[s][ct], acc[nt][ct], 0, 0, 0);
      }
    }
  }
  float asv[4], adv[4];
  #pragma unroll
  for (int ct = 0; ct < 4; ++ct) {
    asv[ct] = as_[w * 64 + ct * 16 + fr];
    adv[ct] = ad_[w * 64 + ct * 16 + fr];
  }
  #pragma unroll
  for (int nt = 0; nt < 4; ++nt) {
    #pragma unroll
    for (int r = 0; r < 4; ++r) {
      int n = n0 + nt * 16 + fq * 4 + r;
      float ps = 0.f, pd = 0.f;
      float rmax = 0.f;
      #pragma unroll
      for (int ct = 0; ct < 4; ++ct) {
        float av = acc[nt][ct][r];
        ps = fmaf(av, asv[ct], ps);
        pd = fmaf(av, adv[ct], pd);
        rmax = fmaxf(rmax, fabsf(av));
      }
      #pragma unroll
      for (int m = 1; m < 16; m <<= 1) {
        ps += __shfl_xor(ps, m, 64);
        pd += __shfl_xor(pd, m, 64);
        rmax = fmaxf(rmax, __shfl_xor(rmax, m, 64));
      }
      float scale = rmax * (1.f / 127.f);
      float qinv = rmax > 0.f ? 127.f / rmax : 0.f;
      if (fr == 0 && n < N) {
        alsc[(size_t)n * 4 + w] = make_float2(ps, scale);
        ald[(size_t)n * 4 + w] = pd;
      }
      if (n < N) {
        #pragma unroll
        for (int ct = 0; ct < 4; ++ct) {
          int iv = __float2int_rn(acc[nt][ct][r] * qinv);
          h8[(size_t)n * 256 + w * 64 + ct * 16 + fr] = (signed char)iv;
        }
      }
    }
  }
}

// ---------------- attention aggregate (int8 h, 4-wide loop) + epilogue [+ fused final] ----------------
template <bool FINAL>
__global__ __launch_bounds__(256) void k_agg(const signed char* __restrict__ h8, const float2* __restrict__ alsc,
                                             const float* __restrict__ ald, const int* __restrict__ off,
                                             const int* __restrict__ csr, const float* __restrict__ bg,
                                             const float* __restrict__ gam, const float* __restrict__ bet,
                                             const float* __restrict__ pa,
                                             short* __restrict__ xhi, short* __restrict__ xlo,
                                             const float* __restrict__ Wp, const float* __restrict__ bp,
                                             float* __restrict__ out, int N) {
  int lane = threadIdx.x & 63;
  int n = blockIdx.x * 4 + (threadIdx.x >> 6);
  if (n >= N) return;
  int hh = lane >> 4;
  int cg = (lane & 15) * 4;
  float aldv = ald[(size_t)n * 4 + hh];
  int e0 = __builtin_amdgcn_readfirstlane(off[n]);
  int e1 = __builtin_amdgcn_readfirstlane(off[n + 1]);
  float a0 = 0, a1 = 0, a2 = 0, a3 = 0, den = 0;
  const int co = hh * 64 + cg;   // byte offset in 256-byte int8 row
  int e = e0;
  for (; e + 4 <= e1; e += 4) {
    int s0 = csr[e + 0], s1 = csr[e + 1], s2 = csr[e + 2], s3 = csr[e + 3];
    float2 p0 = alsc[(size_t)s0 * 4 + hh];
    float2 p1 = alsc[(size_t)s1 * 4 + hh];
    float2 p2 = alsc[(size_t)s2 * 4 + hh];
    float2 p3 = alsc[(size_t)s3 * 4 + hh];
    uchar4 g0 = *(const uchar4*)(h8 + (size_t)s0 * 256 + co);
    uchar4 g1 = *(const uchar4*)(h8 + (size_t)s1 * 256 + co);
    uchar4 g2 = *(const uchar4*)(h8 + (size_t)s2 * 256 + co);
    uchar4 g3 = *(const uchar4*)(h8 + (size_t)s3 * 256 + co);
    float t0 = p0.x + aldv; t0 = fmaxf(t0, 0.2f * t0); float w0 = __expf(t0);
    float t1 = p1.x + aldv; t1 = fmaxf(t1, 0.2f * t1); float w1 = __expf(t1);
    float t2 = p2.x + aldv; t2 = fmaxf(t2, 0.2f * t2); float w2 = __expf(t2);
    float t3 = p3.x + aldv; t3 = fmaxf(t3, 0.2f * t3); float w3 = __expf(t3);
    den += (w0 + w1) + (w2 + w3);
    float ws0 = w0 * p0.y, ws1 = w1 * p1.y, ws2 = w2 * p2.y, ws3 = w3 * p3.y;
    a0 += ws0 * (float)(signed char)g0.x + ws1 * (float)(signed char)g1.x
        + ws2 * (float)(signed char)g2.x + ws3 * (float)(signed char)g3.x;
    a1 += ws0 * (float)(signed char)g0.y + ws1 * (float)(signed char)g1.y
        + ws2 * (float)(signed char)g2.y + ws3 * (float)(signed char)g3.y;
    a2 += ws0 * (float)(signed char)g0.z + ws1 * (float)(signed char)g1.z
        + ws2 * (float)(signed char)g2.z + ws3 * (float)(signed char)g3.z;
    a3 += ws0 * (float)(signed char)g0.w + ws1 * (float)(signed char)g1.w
        + ws2 * (float)(signed char)g2.w + ws3 * (float)(signed char)g3.w;
  }
  for (; e < e1; ++e) {
    int s = csr[e];
    float2 p = alsc[(size_t)s * 4 + hh];
    float t = p.x + aldv;
    t = fmaxf(t, 0.2f * t);
    float w = __expf(t);
    den += w;
    float ws = w * p.y;
    uchar4 g = *(const uchar4*)(h8 + (size_t)s * 256 + co);
    a0 += ws * (float)(signed char)g.x;
    a1 += ws * (float)(signed char)g.y;
    a2 += ws * (float)(signed char)g.z;
    a3 += ws * (float)(signed char)g.w;
  }
  float inv = 1.0f / den;
  a0 *= inv; a1 *= inv; a2 *= inv; a3 *= inv;
  a0 += __shfl_xor(a0, 16, 64); a0 += __shfl_xor(a0, 32, 64);
  a1 += __shfl_xor(a1, 16, 64); a1 += __shfl_xor(a1, 32, 64);
  a2 += __shfl_xor(a2, 16, 64); a2 += __shfl_xor(a2, 32, 64);
  a3 += __shfl_xor(a3, 16, 64); a3 += __shfl_xor(a3, 32, 64);
  float v0 = a0 * 0.25f + bg[cg + 0];
  float v1 = a1 * 0.25f + bg[cg + 1];
  float v2 = a2 * 0.25f + bg[cg + 2];
  float v3 = a3 * 0.25f + bg[cg + 3];
  float sum = v0 + v1 + v2 + v3;
  #pragma unroll
  for (int m = 1; m < 16; m <<= 1) sum += __shfl_xor(sum, m, 64);
  float mu = sum * (1.f / 64.f);
  float d0 = v0 - mu, d1 = v1 - mu, d2 = v2 - mu, d3 = v3 - mu;
  float vv = d0 * d0 + d1 * d1 + d2 * d2 + d3 * d3;
  #pragma unroll
  for (int m = 1; m < 16; m <<= 1) vv += __shfl_xor(vv, m, 64);
  float rstd = rsqrtf(vv * (1.f / 64.f) + 1e-5f);
  float A = pa[0];
  float y0 = d0 * rstd * gam[cg + 0] + bet[cg + 0];
  float y1 = d1 * rstd * gam[cg + 1] + bet[cg + 1];
  float y2 = d2 * rstd * gam[cg + 2] + bet[cg + 2];
  float y3 = d3 * rstd * gam[cg + 3] + bet[cg + 3];
  y0 = y0 > 0.f ? y0 : A * y0;
  y1 = y1 > 0.f ? y1 : A * y1;
  y2 = y2 > 0.f ? y2 : A * y2;
  y3 = y3 > 0.f ? y3 : A * y3;
  // residual row (valid in lanes 0..15, 4 ch each) from split planes
  float o0 = 0.f, o1 = 0.f, o2 = 0.f, o3 = 0.f;
  if (lane < 16) {
    ushort4 xh = *(const ushort4*)((const unsigned short*)xhi + (size_t)n * 64 + cg);
    ushort4 xl = *(const ushort4*)((const unsigned short*)xlo + (size_t)n * 64 + cg);
    o0 = bits2f(xh.x) + bits2f(xl.x) + y0;
    o1 = bits2f(xh.y) + bits2f(xl.y) + y1;
    o2 = bits2f(xh.z) + bits2f(xl.z) + y2;
    o3 = bits2f(xh.w) + bits2f(xl.w) + y3;
  }
  if (!FINAL) {
    if (lane < 16) {
      short h0, l0, h1, l1, h2, l2, h3, l3;
      splitf(o0, h0, l0); splitf(o1, h1, l1); splitf(o2, h2, l2); splitf(o3, h3, l3);
      ushort4 oh = make_ushort4((unsigned short)h0, (unsigned short)h1, (unsigned short)h2, (unsigned short)h3);
      ushort4 ol = make_ushort4((unsigned short)l0, (unsigned short)l1, (unsigned short)l2, (unsigned short)l3);
      *(ushort4*)((unsigned short*)xhi + (size_t)n * 64 + cg) = oh;   // in place: only this wave touches row n
      *(ushort4*)((unsigned short*)xlo + (size_t)n * 64 + cg) = ol;
    }
  } else {
    // z = row @ Wp + bp ; L2-normalize ; out
    float acc = bp[lane];
    #pragma unroll
    for (int g = 0; g < 16; ++g) {
      float rx = __shfl(o0, g, 64), ry = __shfl(o1, g, 64);
      float rz = __shfl(o2, g, 64), rw = __shfl(o3, g, 64);
      const float* wp = Wp + g * 4 * 64 + lane;
      acc = fmaf(rx, wp[0],   acc);
      acc = fmaf(ry, wp[64],  acc);
      acc = fmaf(rz, wp[128], acc);
      acc = fmaf(rw, wp[192], acc);
    }
    float sq = acc * acc;
    #pragma unroll
    for (int m = 1; m < 64; m <<= 1) sq += __shfl_xor(sq, m, 64);
    float nrm = fmaxf(sqrtf(sq), 1e-12f);
    out[(size_t)n * 64 + lane] = acc / nrm;
  }
}

extern "C" void kernel_launch(void* const* d_in, const int* in_sizes, int n_in,
                              void* d_out, int out_size, void* d_ws, size_t ws_size,
                              hipStream_t stream) {
  const float* feat = (const float*)d_in[0];
  const int*   ei   = (const int*)d_in[1];
  const float* Wt   = (const float*)d_in[2];
  const float* bt   = (const float*)d_in[3];
  const float* Wp   = (const float*)d_in[4];
  const float* bp   = (const float*)d_in[5];
  const float* Wg[2]  = {(const float*)d_in[6],  (const float*)d_in[13]};
  const float* as_[2] = {(const float*)d_in[7],  (const float*)d_in[14]};
  const float* ad_[2] = {(const float*)d_in[8],  (const float*)d_in[15]};
  const float* bg[2]  = {(const float*)d_in[9],  (const float*)d_in[16]};
  const float* gm[2]  = {(const float*)d_in[10], (const float*)d_in[17]};
  const float* be[2]  = {(const float*)d_in[11], (const float*)d_in[18]};
  const float* pa[2]  = {(const float*)d_in[12], (const float*)d_in[19]};

  const int N = in_sizes[0] / 512;
  const int E = in_sizes[1] / 2;

  // workspace layout
  short* xhi = (short*)d_ws;                                  // N*64 bf16-hi plane
  short* xlo = xhi + (size_t)N * 64;                          // N*64 bf16-lo plane
  signed char* h8 = (signed char*)(xlo + (size_t)N * 64);     // N*256 int8
  float2* alsc = (float2*)(h8 + (size_t)N * 256);             // N*4 float2 {als, scale}
  float* ald = (float*)(alsc + (size_t)N * 4);                // N*4
  int* cnt = (int*)(ald + (size_t)N * 4);                     // N
  int* cur = cnt + N;                                         // N
  int* csr = cur + N;                                         // E+N
  int* off = csr + (E + N);                                   // N+1
  int* bsum = off + (N + 1);                                  // 16
  short* pk0 = (short*)(((uintptr_t)(bsum + 16) + 15) & ~(uintptr_t)15);  // 32768 shorts
  short* pk1 = pk0 + 32768;
  short* wtpk = pk1 + 32768;                                  // 65536 shorts

  hipMemsetAsync(cnt, 0, (size_t)N * sizeof(int), stream);
  int eb = (E + N + 255) / 256;
  int SB = (N + 4095) / 4096;
  k_degree<<<eb, 256, 0, stream>>>(ei, cnt, E, N);
  k_prep<<<128, 64, 0, stream>>>(Wg[0], Wg[1], Wt, pk0, pk1, wtpk);
  k_scan_blk<<<SB, 1024, 0, stream>>>(cnt, off, bsum, N);
  k_scan_add<<<SB, 1024, 0, stream>>>(off, cur, bsum, E + N, N);
  k_scatter<<<eb, 256, 0, stream>>>(ei, cur, csr, E, N);

  int nb4 = (N + 3) / 4;
  int nb64 = (N + 63) / 64;
  int nb128 = (N + 127) / 128;
  k_x0<<<nb128, 256, 0, stream>>>(feat, wtpk, bt, xhi, xlo, N);

  k_h<<<nb64, 256, 0, stream>>>(xhi, xlo, pk0, as_[0], ad_[0], h8, alsc, ald, N);
  k_agg<false><<<nb4, 256, 0, stream>>>(h8, alsc, ald, off, csr, bg[0], gm[0], be[0], pa[0],
                                        xhi, xlo, Wp, bp, (float*)d_out, N);
  k_h<<<nb64, 256, 0, stream>>>(xhi, xlo, pk1, as_[1], ad_[1], h8, alsc, ald, N);
  k_agg<true><<<nb4, 256, 0, stream>>>(h8, alsc, ald, off, csr, bg[1], gm[1], be[1], pa[1],
                                       xhi, xlo, Wp, bp, (float*)d_out, N);
}